// Round 1
// baseline (94.227 us; speedup 1.0000x reference)
//
#include <hip/hip_runtime.h>
#include <math.h>

#define NDIM 64
#define NG (64*64*64)
#define NA 128
#define NK 6

// ---------------------------------------------------------------------------
// 1) Density: rho[g] = sum_a sum_k aw[a,k] * exp(bw[a,k] * |g - x_a|^2)
//    Grid coords are exactly idx*0.5 (from reference arange*SPACING).
//    Writes complex (rho, 0) into W.
// ---------------------------------------------------------------------------
__global__ __launch_bounds__(256) void density_kernel(
    const float* __restrict__ X, const float* __restrict__ aw,
    const float* __restrict__ bw, float2* __restrict__ W)
{
    int g = blockIdx.x * 256 + threadIdx.x;
    int z = g & 63, y = (g >> 6) & 63, x = g >> 12;
    float px = (float)x * 0.5f, py = (float)y * 0.5f, pz = (float)z * 0.5f;
    float dens = 0.f;
    for (int a = 0; a < NA; ++a) {
        float dx = px - X[a * 3 + 0];
        float dy = py - X[a * 3 + 1];
        float dz = pz - X[a * 3 + 2];
        float d2 = dx * dx + dy * dy + dz * dz;
#pragma unroll
        for (int k = 0; k < NK; ++k) {
            dens += aw[a * NK + k] * __expf(bw[a * NK + k] * d2);
        }
    }
    W[g] = make_float2(dens, 0.f);
}

// ---------------------------------------------------------------------------
// 2) Per-line 64-point DFT passes (brute force O(N^2) per line, natural order).
//    AXIS: 2 = z (stride 1), 1 = y (stride 64), 0 = x (stride 4096).
//    INVERSE flips twiddle sign. APPLY_H multiplies by shifted Hamming on load
//    (first inverse pass). WRITE_REAL writes scaled real part to out (last
//    inverse pass); scale = 1/N^3 (ortho fwd+inv pair == standard pair).
// ---------------------------------------------------------------------------
template <int AXIS, bool INVERSE, bool APPLY_H, bool WRITE_REAL>
__global__ __launch_bounds__(256) void fft_pass(
    float2* __restrict__ W, const float* __restrict__ ham,
    float* __restrict__ outr)
{
    __shared__ float2 tw[64];
    __shared__ float2 ln[4][65];   // +1 pad: 4 lines land in distinct banks

    int tid = threadIdx.x;
    int k = tid & 63;
    int lid = tid >> 6;

    if (tid < 64) {
        float ang = (INVERSE ? 6.28318530717958647692f
                             : -6.28318530717958647692f) * (float)tid / 64.0f;
        float s, c;
        sincosf(ang, &s, &c);
        tw[tid] = make_float2(c, s);
    }

    int L = blockIdx.x * 4 + lid;   // line index 0..4095
    int a = L >> 6, b = L & 63;
    int base, stride;
    if (AXIS == 2)      { base = a * 4096 + b * 64; stride = 1; }
    else if (AXIS == 1) { base = a * 4096 + b;      stride = 64; }
    else                { base = a * 64 + b;        stride = 4096; }

    float2 v = W[base + k * stride];
    if (APPLY_H) {
        int hx, hy, hz;
        if (AXIS == 2)      { hx = a; hy = b; hz = k; }
        else if (AXIS == 1) { hx = a; hy = k; hz = b; }
        else                { hx = k; hy = a; hz = b; }
        float h = ham[((hx + 32) & 63) * 4096 + ((hy + 32) & 63) * 64 +
                      ((hz + 32) & 63)];
        v.x *= h;
        v.y *= h;
    }
    ln[lid][k] = v;
    __syncthreads();

    float re = 0.f, im = 0.f;
#pragma unroll 8
    for (int n = 0; n < 64; ++n) {
        float2 xv = ln[lid][n];
        float2 t = tw[(n * k) & 63];
        re += xv.x * t.x - xv.y * t.y;
        im += xv.x * t.y + xv.y * t.x;
    }

    if (WRITE_REAL) {
        outr[base + k * stride] = re * (1.0f / 262144.0f);
    } else {
        W[base + k * stride] = make_float2(re, im);
    }
}

// ---------------------------------------------------------------------------
// 3) Deterministic two-stage mean/var reduction + normalize.
// ---------------------------------------------------------------------------
__global__ __launch_bounds__(256) void reduce1_kernel(
    const float* __restrict__ y, double* __restrict__ partial)
{
    int g = blockIdx.x * 256 + threadIdx.x;
    float v = y[g];
    double s = (double)v;
    double s2 = (double)v * (double)v;
#pragma unroll
    for (int off = 32; off > 0; off >>= 1) {
        s += __shfl_down(s, off, 64);
        s2 += __shfl_down(s2, off, 64);
    }
    __shared__ double ls[4], ls2[4];
    int lane = threadIdx.x & 63, w = threadIdx.x >> 6;
    if (lane == 0) { ls[w] = s; ls2[w] = s2; }
    __syncthreads();
    if (threadIdx.x == 0) {
        partial[2 * blockIdx.x + 0] = ls[0] + ls[1] + ls[2] + ls[3];
        partial[2 * blockIdx.x + 1] = ls2[0] + ls2[1] + ls2[2] + ls2[3];
    }
}

__global__ __launch_bounds__(256) void reduce2_kernel(
    const double* __restrict__ partial, double* __restrict__ acc)
{
    // 1024 blocks of partials; 256 threads each take 4 (fixed order).
    int t = threadIdx.x;
    double s = 0.0, s2 = 0.0;
#pragma unroll
    for (int i = 0; i < 4; ++i) {
        s += partial[2 * (t + 256 * i) + 0];
        s2 += partial[2 * (t + 256 * i) + 1];
    }
    __shared__ double ls[256], ls2[256];
    ls[t] = s; ls2[t] = s2;
    __syncthreads();
    for (int off = 128; off > 0; off >>= 1) {
        if (t < off) { ls[t] += ls[t + off]; ls2[t] += ls2[t + off]; }
        __syncthreads();
    }
    if (t == 0) { acc[0] = ls[0]; acc[1] = ls2[0]; }
}

__global__ __launch_bounds__(256) void normalize_kernel(
    float* __restrict__ y, const double* __restrict__ acc)
{
    int g = blockIdx.x * 256 + threadIdx.x;
    double mean = acc[0] * (1.0 / (double)NG);
    double var = acc[1] * (1.0 / (double)NG) - mean * mean;
    float stdv = (float)sqrt(var > 0.0 ? var : 0.0);
    y[g] = ((y[g] - (float)mean) / (stdv + 1e-8f));
}

// ---------------------------------------------------------------------------
extern "C" void kernel_launch(void* const* d_in, const int* in_sizes, int n_in,
                              void* d_out, int out_size, void* d_ws,
                              size_t ws_size, hipStream_t stream)
{
    const float* X   = (const float*)d_in[0];
    const float* aw  = (const float*)d_in[1];
    const float* bw  = (const float*)d_in[2];
    // d_in[3] = real_grid_flat (unused: coords are exactly idx*0.5)
    const float* ham = (const float*)d_in[4];
    float* out = (float*)d_out;

    float2* W = (float2*)d_ws;                                   // 2 MiB
    double* partial = (double*)((char*)d_ws + (size_t)NG * sizeof(float2));
    double* acc = partial + 2 * 1024;

    density_kernel<<<NG / 256, 256, 0, stream>>>(X, aw, bw, W);

    // forward FFT (unnormalized DFT), natural order throughout
    fft_pass<2, false, false, false><<<1024, 256, 0, stream>>>(W, ham, nullptr);
    fft_pass<1, false, false, false><<<1024, 256, 0, stream>>>(W, ham, nullptr);
    fft_pass<0, false, false, false><<<1024, 256, 0, stream>>>(W, ham, nullptr);

    // inverse FFT; Hamming (ifftshifted indexing) fused into first pass,
    // real part + 1/N^3 written by last pass
    fft_pass<2, true, true, false><<<1024, 256, 0, stream>>>(W, ham, nullptr);
    fft_pass<1, true, false, false><<<1024, 256, 0, stream>>>(W, ham, nullptr);
    fft_pass<0, true, false, true><<<1024, 256, 0, stream>>>(W, ham, out);

    reduce1_kernel<<<1024, 256, 0, stream>>>(out, partial);
    reduce2_kernel<<<1, 256, 0, stream>>>(partial, acc);
    normalize_kernel<<<1024, 256, 0, stream>>>(out, acc);
}

// Round 2
// 67.897 us; speedup vs baseline: 1.3878x; 1.3878x over previous
//
#include <hip/hip_runtime.h>
#include <math.h>

#define NG (64*64*64)
#define NAK 768          // 128 atoms * 6 terms

// ---- workspace layout (bytes) ----
#define WS_W    0                       // float2[NG]  2 MiB
#define WS_R    (2*1024*1024)           // float[NG]   1 MiB
#define WS_TXA  (3*1024*1024)           // float[64][768] (aw folded)
#define WS_TY   (WS_TXA + 768*64*4)     // float[64][768]
#define WS_EZ   (WS_TY  + 768*64*4)     // float[768][64]
#define WS_PART (WS_EZ  + 768*64*4)     // double[512]
#define WS_ACC  (WS_PART + 512*8)       // double[2]

// ---------------------------------------------------------------------------
// Tables: Txa[c][ak] = aw*exp(bw*(0.5c-X0)^2); Ty[c][ak]; Ez[ak][c].
// grid (3, 64, 3): ak = bx*256+t, c = by, axis = bz.
// ---------------------------------------------------------------------------
__global__ __launch_bounds__(256) void table_kernel(
    const float* __restrict__ X, const float* __restrict__ aw,
    const float* __restrict__ bw, float* __restrict__ Txa,
    float* __restrict__ Ty, float* __restrict__ Ez)
{
    int ak = blockIdx.x * 256 + threadIdx.x;   // 0..767
    int c = blockIdx.y;
    int axis = blockIdx.z;
    int a = ak / 6;
    float d = 0.5f * (float)c - X[a * 3 + axis];
    float e = __expf(bw[ak] * d * d);
    if (axis == 0)      Txa[c * 768 + ak] = e * aw[ak];
    else if (axis == 1) Ty[c * 768 + ak] = e;
    else                Ez[ak * 64 + c] = e;
}

// ---------------------------------------------------------------------------
// Density: rho[xy][z] = sum_j Txa[x][j]*Ty[y][j]*Ez[j][z].
// Block: 16 rows (one x, 16 consecutive y), 256 threads; wave = 4 rows x 64 z.
// Tx/Ty rows are wave-uniform -> scalar loads; Ez coalesced vector loads.
// ---------------------------------------------------------------------------
__global__ __launch_bounds__(256) void density_kernel(
    const float* __restrict__ Txa, const float* __restrict__ Ty,
    const float* __restrict__ Ez, float* __restrict__ R)
{
    int tid = threadIdx.x;
    int z = tid & 63;
    int w = tid >> 6;
    int xy0 = blockIdx.x * 16;
    int xu  = __builtin_amdgcn_readfirstlane(xy0 >> 6);
    int r0u = __builtin_amdgcn_readfirstlane(xy0 + w * 4);
    const float* tx  = Txa + xu * 768;
    const float* ty0 = Ty + (r0u & 63) * 768;
    const float* ty1 = ty0 + 768;
    const float* ty2 = ty0 + 1536;
    const float* ty3 = ty0 + 2304;
    const float* ezp = Ez + z;
    float a0 = 0.f, a1 = 0.f, a2 = 0.f, a3 = 0.f;
    for (int j = 0; j < 768; j += 8) {
#pragma unroll
        for (int i = 0; i < 8; ++i) {
            float ez  = ezp[(j + i) * 64];
            float txe = tx[j + i] * ez;
            a0 += ty0[j + i] * txe;
            a1 += ty1[j + i] * txe;
            a2 += ty2[j + i] * txe;
            a3 += ty3[j + i] * txe;
        }
    }
    R[(r0u + 0) * 64 + z] = a0;
    R[(r0u + 1) * 64 + z] = a1;
    R[(r0u + 2) * 64 + z] = a2;
    R[(r0u + 3) * 64 + z] = a3;
}

// ---------------------------------------------------------------------------
// 8-point DFT, constants folded at compile time. conj=true -> inverse.
// ---------------------------------------------------------------------------
__device__ __forceinline__ void dft8(const float xr[8], const float xi[8],
                                     float yr[8], float yi[8], bool conj)
{
    const float rt = 0.70710678118654752f;
    const float C[8]  = {1.f, rt, 0.f, -rt, -1.f, -rt, 0.f, rt};
    const float Sf[8] = {0.f, -rt, -1.f, -rt, 0.f, rt, 1.f, rt};
#pragma unroll
    for (int k = 0; k < 8; ++k) {
        float ar = 0.f, ai = 0.f;
#pragma unroll
        for (int n = 0; n < 8; ++n) {
            float c = C[(n * k) & 7];
            float s = conj ? -Sf[(n * k) & 7] : Sf[(n * k) & 7];
            ar += xr[n] * c - xi[n] * s;
            ai += xr[n] * s + xi[n] * c;
        }
        yr[k] = ar; yi[k] = ai;
    }
}

// 64-pt transform: x[n2] holds element 8*n2+t; returns y[k2] = element t+8*k2.
// tw = FORWARD twiddle table; CONJ=true -> inverse transform.
template <bool CONJ>
__device__ __forceinline__ void xform64(float2 x[8], float2 y[8],
    float2 (*ln)[66], int lid, int t, const float2* tw)
{
    float xr[8], xi[8], br[8], bi[8];
#pragma unroll
    for (int n = 0; n < 8; ++n) { xr[n] = x[n].x; xi[n] = x[n].y; }
    dft8(xr, xi, br, bi, CONJ);
#pragma unroll
    for (int k1 = 0; k1 < 8; ++k1) {           // B = A * W64^{t*k1}
        float2 wv = tw[(t * k1) & 63];
        float ws = CONJ ? -wv.y : wv.y;
        float tr = br[k1] * wv.x - bi[k1] * ws;
        float ti = br[k1] * ws + bi[k1] * wv.x;
        br[k1] = tr; bi[k1] = ti;
    }
    __syncthreads();                            // prior ln use complete
#pragma unroll
    for (int k1 = 0; k1 < 8; ++k1)
        ln[lid][k1 * 8 + t] = make_float2(br[k1], bi[k1]);
    __syncthreads();
#pragma unroll
    for (int n1 = 0; n1 < 8; ++n1) {
        float2 v = ln[lid][t * 8 + n1];
        xr[n1] = v.x; xi[n1] = v.y;
    }
    dft8(xr, xi, br, bi, CONJ);
#pragma unroll
    for (int k2 = 0; k2 < 8; ++k2) y[k2] = make_float2(br[k2], bi[k2]);
}

// ---------------------------------------------------------------------------
// Radix-8^2 FFT pass. 128 threads = 16 lines x 8 threads; grid 256.
// FUSED (axis x): fwd DFT + Hamming + inv DFT in one kernel.
// WRITE_REAL: write scaled real part + block partial sums (fused reduce1).
// ---------------------------------------------------------------------------
template <int AXIS, bool INV, bool REAL_IN, bool FUSED, bool WRITE_REAL>
__global__ __launch_bounds__(128) void fft8_pass(
    const float* __restrict__ rin, float2* __restrict__ W,
    const float* __restrict__ ham, float* __restrict__ outr,
    double* __restrict__ partial)
{
    __shared__ float2 tw[64];
    __shared__ float2 ln[16][66];
    __shared__ double red[4];

    int tid = threadIdx.x;
    if (tid < 64) {
        float ang = -6.28318530717958647692f * (float)tid / 64.0f;  // forward
        float s, c;
        sincosf(ang, &s, &c);
        tw[tid] = make_float2(c, s);
    }
    __syncthreads();

    int lid = tid >> 3, t = tid & 7;
    int L = blockIdx.x * 16 + lid;
    int a = L >> 6, b = L & 63;
    int base, stride;
    if (AXIS == 2)      { base = a * 4096 + b * 64; stride = 1; }
    else if (AXIS == 1) { base = a * 4096 + b;      stride = 64; }
    else                { base = a * 64 + b;        stride = 4096; }

    float2 x[8], y[8];
#pragma unroll
    for (int n2 = 0; n2 < 8; ++n2) {
        int idx = base + (8 * n2 + t) * stride;
        if (REAL_IN) x[n2] = make_float2(rin[idx], 0.f);
        else         x[n2] = W[idx];
    }
    xform64<INV>(x, y, ln, lid, t, tw);

    if (FUSED) {
        // coords here: x-freq = k, y-freq = a, z-freq = b
        int hyz = ((a + 32) & 63) * 64 + ((b + 32) & 63);
#pragma unroll
        for (int k2 = 0; k2 < 8; ++k2) {
            int kx = t + 8 * k2;
            float h = ham[((kx + 32) & 63) * 4096 + hyz];
            y[k2].x *= h; y[k2].y *= h;
        }
        __syncthreads();                 // all stage-2 reads done
#pragma unroll
        for (int k2 = 0; k2 < 8; ++k2) ln[lid][t + 8 * k2] = y[k2];
        __syncthreads();
#pragma unroll
        for (int n2 = 0; n2 < 8; ++n2) x[n2] = ln[lid][8 * n2 + t];
        xform64<true>(x, y, ln, lid, t, tw);   // inverse
    }

    if (WRITE_REAL) {
        double s1 = 0.0, s2 = 0.0;
#pragma unroll
        for (int k2 = 0; k2 < 8; ++k2) {
            float v = y[k2].x * (1.0f / 262144.0f);
            outr[base + (t + 8 * k2) * stride] = v;
            s1 += (double)v;
            s2 += (double)v * (double)v;
        }
#pragma unroll
        for (int off = 32; off > 0; off >>= 1) {
            s1 += __shfl_down(s1, off, 64);
            s2 += __shfl_down(s2, off, 64);
        }
        int lane = tid & 63, wv = tid >> 6;
        if (lane == 0) { red[wv * 2] = s1; red[wv * 2 + 1] = s2; }
        __syncthreads();
        if (tid == 0) {
            partial[blockIdx.x * 2 + 0] = red[0] + red[2];
            partial[blockIdx.x * 2 + 1] = red[1] + red[3];
        }
    } else {
#pragma unroll
        for (int k2 = 0; k2 < 8; ++k2)
            W[base + (t + 8 * k2) * stride] = y[k2];
    }
}

// ---------------------------------------------------------------------------
__global__ __launch_bounds__(256) void reduce2_kernel(
    const double* __restrict__ partial, double* __restrict__ acc)
{
    int t = threadIdx.x;
    __shared__ double ls[256], ls2[256];
    ls[t] = partial[2 * t];
    ls2[t] = partial[2 * t + 1];
    __syncthreads();
    for (int off = 128; off > 0; off >>= 1) {
        if (t < off) { ls[t] += ls[t + off]; ls2[t] += ls2[t + off]; }
        __syncthreads();
    }
    if (t == 0) { acc[0] = ls[0]; acc[1] = ls2[0]; }
}

__global__ __launch_bounds__(256) void normalize_kernel(
    float* __restrict__ yv, const double* __restrict__ acc)
{
    int g = blockIdx.x * 256 + threadIdx.x;
    double mean = acc[0] * (1.0 / (double)NG);
    double var = acc[1] * (1.0 / (double)NG) - mean * mean;
    float stdv = (float)sqrt(var > 0.0 ? var : 0.0);
    yv[g] = (yv[g] - (float)mean) / (stdv + 1e-8f);
}

// ---------------------------------------------------------------------------
extern "C" void kernel_launch(void* const* d_in, const int* in_sizes, int n_in,
                              void* d_out, int out_size, void* d_ws,
                              size_t ws_size, hipStream_t stream)
{
    const float* X   = (const float*)d_in[0];
    const float* aw  = (const float*)d_in[1];
    const float* bw  = (const float*)d_in[2];
    const float* ham = (const float*)d_in[4];
    float* out = (float*)d_out;

    char* ws = (char*)d_ws;
    float2* W      = (float2*)(ws + WS_W);
    float*  R      = (float*)(ws + WS_R);
    float*  Txa    = (float*)(ws + WS_TXA);
    float*  Ty     = (float*)(ws + WS_TY);
    float*  Ez     = (float*)(ws + WS_EZ);
    double* part   = (double*)(ws + WS_PART);
    double* acc    = (double*)(ws + WS_ACC);

    table_kernel<<<dim3(3, 64, 3), 256, 0, stream>>>(X, aw, bw, Txa, Ty, Ez);
    density_kernel<<<256, 256, 0, stream>>>(Txa, Ty, Ez, R);

    // fwd z, fwd y, [fwd x + H + inv x], inv y, inv z(+real+reduce)
    fft8_pass<2, false, true,  false, false><<<256, 128, 0, stream>>>(R, W, ham, nullptr, nullptr);
    fft8_pass<1, false, false, false, false><<<256, 128, 0, stream>>>(nullptr, W, ham, nullptr, nullptr);
    fft8_pass<0, false, false, true,  false><<<256, 128, 0, stream>>>(nullptr, W, ham, nullptr, nullptr);
    fft8_pass<1, true,  false, false, false><<<256, 128, 0, stream>>>(nullptr, W, ham, nullptr, nullptr);
    fft8_pass<2, true,  false, false, true ><<<256, 128, 0, stream>>>(nullptr, W, ham, out, part);

    reduce2_kernel<<<1, 256, 0, stream>>>(part, acc);
    normalize_kernel<<<1024, 256, 0, stream>>>(out, acc);
}

// Round 3
// 65.290 us; speedup vs baseline: 1.4432x; 1.0399x over previous
//
#include <hip/hip_runtime.h>
#include <math.h>

#define NG (64*64*64)

// ---- workspace layout (bytes) ----
#define WS_W    0                        // float2[NG]  2 MiB   (layout W2[kz][x][y])
#define WS_TXA  (2*1024*1024)            // float[64][768] (aw folded)
#define WS_TY   (WS_TXA + 768*64*4)      // float[64][768]
#define WS_EZ   (WS_TY  + 768*64*4)      // float[768][64]
#define WS_TW   (WS_EZ  + 768*64*4)      // float2[64] forward twiddles
#define WS_PART (WS_TW  + 64*8)          // double[256]

// ---------------------------------------------------------------------------
// K1: per-axis Gaussian tables + forward twiddle table.
// ---------------------------------------------------------------------------
__global__ __launch_bounds__(256) void table_kernel(
    const float* __restrict__ X, const float* __restrict__ aw,
    const float* __restrict__ bw, float* __restrict__ Txa,
    float* __restrict__ Ty, float* __restrict__ Ez, float2* __restrict__ twg)
{
    int tid = threadIdx.x;
    if (blockIdx.x == 0 && blockIdx.y == 0 && blockIdx.z == 0 && tid < 64) {
        float ang = -6.28318530717958647692f * (float)tid / 64.0f;
        float s, c;
        sincosf(ang, &s, &c);
        twg[tid] = make_float2(c, s);
    }
    int ak = blockIdx.x * 256 + tid;   // 0..767
    int c = blockIdx.y;
    int axis = blockIdx.z;
    int a = ak / 6;
    float d = 0.5f * (float)c - X[a * 3 + axis];
    float e = __expf(bw[ak] * d * d);
    if (axis == 0)      Txa[c * 768 + ak] = e * aw[ak];
    else if (axis == 1) Ty[c * 768 + ak] = e;
    else                Ez[ak * 64 + c] = e;
}

// ---------------------------------------------------------------------------
// 8-point DFT with folded constants. conj=true -> inverse sign.
// ---------------------------------------------------------------------------
__device__ __forceinline__ void dft8(const float xr[8], const float xi[8],
                                     float yr[8], float yi[8], bool conj)
{
    const float rt = 0.70710678118654752f;
    const float C[8]  = {1.f, rt, 0.f, -rt, -1.f, -rt, 0.f, rt};
    const float Sf[8] = {0.f, -rt, -1.f, -rt, 0.f, rt, 1.f, rt};
#pragma unroll
    for (int k = 0; k < 8; ++k) {
        float ar = 0.f, ai = 0.f;
#pragma unroll
        for (int n = 0; n < 8; ++n) {
            float c = C[(n * k) & 7];
            float s = conj ? -Sf[(n * k) & 7] : Sf[(n * k) & 7];
            ar += xr[n] * c - xi[n] * s;
            ai += xr[n] * s + xi[n] * c;
        }
        yr[k] = ar; yi[k] = ai;
    }
}

// 64-pt transform, radix 8x8, 8 threads/line. Input xin[n2] = element 8*n2+t
// (loaded by caller). Uses L[(...)*es] as the per-line exchange buffer
// (B-write slots == slots this thread loaded xin from -> no pre-barrier
// needed). Internal block barrier between B write and B' read; ALL threads
// of the block must call this (inactive threads skip compute, hit barrier).
// Output y[k2] = element t+8*k2.
__device__ __forceinline__ void xf64(const float2 xin[8], float2* L, int es,
                                     int t, bool conj, const float2* tw,
                                     float2 y[8], bool active)
{
    float br[8], bi[8];
    if (active) {
        float xr[8], xi[8];
#pragma unroll
        for (int n = 0; n < 8; ++n) { xr[n] = xin[n].x; xi[n] = xin[n].y; }
        dft8(xr, xi, br, bi, conj);
#pragma unroll
        for (int k1 = 0; k1 < 8; ++k1) {
            float2 wv = tw[(t * k1) & 63];
            float ws = conj ? -wv.y : wv.y;
            float tr = br[k1] * wv.x - bi[k1] * ws;
            float ti = br[k1] * ws + bi[k1] * wv.x;
            br[k1] = tr; bi[k1] = ti;
        }
#pragma unroll
        for (int k1 = 0; k1 < 8; ++k1)
            L[(k1 * 8 + t) * es] = make_float2(br[k1], bi[k1]);
    }
    __syncthreads();
    if (active) {
        float xr[8], xi[8];
#pragma unroll
        for (int n1 = 0; n1 < 8; ++n1) {
            float2 v = L[(t * 8 + n1) * es];
            xr[n1] = v.x; xi[n1] = v.y;
        }
        dft8(xr, xi, br, bi, conj);
#pragma unroll
        for (int k2 = 0; k2 < 8; ++k2) y[k2] = make_float2(br[k2], bi[k2]);
    }
}

// ---------------------------------------------------------------------------
// K2: density + forward z-FFT. Block = 16 rows (one x, 16 y), 256 threads.
// Density: wave w computes rows xy0+4w..+3, lane = z. Then 16 z-lines are
// FFT'd in LDS (128 active threads) and written to W2[kz][x][y].
// ---------------------------------------------------------------------------
__global__ __launch_bounds__(256) void density_fftz_kernel(
    const float* __restrict__ Txa, const float* __restrict__ Ty,
    const float* __restrict__ Ez, const float2* __restrict__ twg,
    float2* __restrict__ W2)
{
    __shared__ float2 D[16][66];
    __shared__ float2 tw[64];
    int tid = threadIdx.x;
    if (tid < 64) tw[tid] = twg[tid];

    int z = tid & 63;
    int w = tid >> 6;
    int xy0 = blockIdx.x * 16;
    int xu  = __builtin_amdgcn_readfirstlane(xy0 >> 6);
    int r0u = __builtin_amdgcn_readfirstlane(xy0 + w * 4);
    const float* tx  = Txa + xu * 768;
    const float* ty0 = Ty + (r0u & 63) * 768;
    const float* ty1 = ty0 + 768;
    const float* ty2 = ty0 + 1536;
    const float* ty3 = ty0 + 2304;
    const float* ezp = Ez + z;
    float a0 = 0.f, a1 = 0.f, a2 = 0.f, a3 = 0.f;
    for (int j = 0; j < 768; j += 8) {
#pragma unroll
        for (int i = 0; i < 8; ++i) {
            float ez  = ezp[(j + i) * 64];
            float txe = tx[j + i] * ez;
            a0 += ty0[j + i] * txe;
            a1 += ty1[j + i] * txe;
            a2 += ty2[j + i] * txe;
            a3 += ty3[j + i] * txe;
        }
    }
    int rl = w * 4;
    D[rl + 0][z] = make_float2(a0, 0.f);
    D[rl + 1][z] = make_float2(a1, 0.f);
    D[rl + 2][z] = make_float2(a2, 0.f);
    D[rl + 3][z] = make_float2(a3, 0.f);
    __syncthreads();

    bool active = tid < 128;
    int lid = (tid >> 3) & 15, t = tid & 7;
    float2 xin[8], y[8];
    if (active) {
#pragma unroll
        for (int n2 = 0; n2 < 8; ++n2) xin[n2] = D[lid][8 * n2 + t];
    }
    xf64(xin, &D[lid][0], 1, t, false, tw, y, active);
    if (active) {
        int ybase = (xy0 & 63) + lid;
#pragma unroll
        for (int k2 = 0; k2 < 8; ++k2)
            W2[(t + 8 * k2) * 4096 + xu * 64 + ybase] = y[k2];
    }
}

// ---------------------------------------------------------------------------
// K3: per-kz plane kernel: fwd-y, fwd-x, xHamming, inv-x, inv-y, in LDS.
// 64 blocks x 512 threads (64 lines x 8 threads per stage).
// ---------------------------------------------------------------------------
__global__ __launch_bounds__(512) void plane_kernel(
    float2* __restrict__ W2, const float* __restrict__ ham,
    const float2* __restrict__ twg)
{
    __shared__ float2 P[64][66];
    __shared__ float2 tw[64];
    int tid = threadIdx.x;
    if (tid < 64) tw[tid] = twg[tid];

    int z0 = blockIdx.x;
    const float4* src = (const float4*)(W2 + z0 * 4096);
#pragma unroll
    for (int q = 0; q < 4; ++q) {
        int i = tid + q * 512;          // float4 index (2 complex elements)
        float4 v = src[i];
        int e = i * 2;
        P[e >> 6][e & 63] = make_float2(v.x, v.y);
        P[e >> 6][(e & 63) + 1] = make_float2(v.z, v.w);
    }
    __syncthreads();

    int lid = tid >> 3, t = tid & 7;
    float2 xin[8], y[8];

    // forward y (lines = rows x = lid)
#pragma unroll
    for (int n2 = 0; n2 < 8; ++n2) xin[n2] = P[lid][8 * n2 + t];
    xf64(xin, &P[lid][0], 1, t, false, tw, y, true);
    __syncthreads();
#pragma unroll
    for (int k2 = 0; k2 < 8; ++k2) P[lid][t + 8 * k2] = y[k2];
    __syncthreads();

    // forward x (lines = columns y = lid, elem stride 66)
#pragma unroll
    for (int n2 = 0; n2 < 8; ++n2) xin[n2] = P[8 * n2 + t][lid];
    xf64(xin, &P[0][lid], 66, t, false, tw, y, true);
    // Hamming (ifftshift folded: +32 mod 64 on each freq index)
    {
        int hyz = ((lid + 32) & 63) * 64 + ((z0 + 32) & 63);
#pragma unroll
        for (int k2 = 0; k2 < 8; ++k2) {
            int kx = t + 8 * k2;
            float h = ham[((kx + 32) & 63) * 4096 + hyz];
            y[k2].x *= h; y[k2].y *= h;
        }
    }
    __syncthreads();
#pragma unroll
    for (int k2 = 0; k2 < 8; ++k2) P[t + 8 * k2][lid] = y[k2];
    __syncthreads();

    // inverse x
#pragma unroll
    for (int n2 = 0; n2 < 8; ++n2) xin[n2] = P[8 * n2 + t][lid];
    xf64(xin, &P[0][lid], 66, t, true, tw, y, true);
    __syncthreads();
#pragma unroll
    for (int k2 = 0; k2 < 8; ++k2) P[t + 8 * k2][lid] = y[k2];
    __syncthreads();

    // inverse y, write back to global
#pragma unroll
    for (int n2 = 0; n2 < 8; ++n2) xin[n2] = P[lid][8 * n2 + t];
    xf64(xin, &P[lid][0], 1, t, true, tw, y, true);
#pragma unroll
    for (int k2 = 0; k2 < 8; ++k2)
        W2[z0 * 4096 + lid * 64 + t + 8 * k2] = y[k2];
}

// ---------------------------------------------------------------------------
// K4: inverse z-FFT + real + 1/N^3 scale + per-block partial sums.
// 128 blocks x 256 threads (32 lines x 8 threads).
// ---------------------------------------------------------------------------
__global__ __launch_bounds__(256) void invz_kernel(
    const float2* __restrict__ W2, const float2* __restrict__ twg,
    float* __restrict__ outr, double* __restrict__ partial)
{
    __shared__ float2 ln[32][66];
    __shared__ float2 tw[64];
    __shared__ double red[8];
    int tid = threadIdx.x;
    if (tid < 64) tw[tid] = twg[tid];
    __syncthreads();

    int lid = tid >> 3, t = tid & 7;
    int L = blockIdx.x * 32 + lid;      // (x,y) line id, x=L>>6, y=L&63
    float2 xin[8], y[8];
#pragma unroll
    for (int n2 = 0; n2 < 8; ++n2) xin[n2] = W2[(8 * n2 + t) * 4096 + L];
    xf64(xin, &ln[lid][0], 1, t, true, tw, y, true);

    double s1 = 0.0, s2 = 0.0;
#pragma unroll
    for (int k2 = 0; k2 < 8; ++k2) {
        float v = y[k2].x * (1.0f / 262144.0f);
        outr[L * 64 + t + 8 * k2] = v;
        s1 += (double)v;
        s2 += (double)v * (double)v;
    }
#pragma unroll
    for (int off = 32; off > 0; off >>= 1) {
        s1 += __shfl_down(s1, off, 64);
        s2 += __shfl_down(s2, off, 64);
    }
    int lane = tid & 63, wv = tid >> 6;
    if (lane == 0) { red[wv * 2] = s1; red[wv * 2 + 1] = s2; }
    __syncthreads();
    if (tid == 0) {
        partial[blockIdx.x * 2 + 0] = red[0] + red[2] + red[4] + red[6];
        partial[blockIdx.x * 2 + 1] = red[1] + red[3] + red[5] + red[7];
    }
}

// ---------------------------------------------------------------------------
// K5: normalize with inlined final reduction over 128 block partials.
// ---------------------------------------------------------------------------
__global__ __launch_bounds__(256) void norm_kernel(
    float* __restrict__ yv, const double* __restrict__ partial)
{
    __shared__ double ls[128], ls2[128];
    __shared__ float mb[2];
    int t = threadIdx.x;
    if (t < 128) { ls[t] = partial[2 * t]; ls2[t] = partial[2 * t + 1]; }
    __syncthreads();
    for (int off = 64; off > 0; off >>= 1) {
        if (t < off) { ls[t] += ls[t + off]; ls2[t] += ls2[t + off]; }
        __syncthreads();
    }
    if (t == 0) {
        double mean = ls[0] * (1.0 / (double)NG);
        double var = ls2[0] * (1.0 / (double)NG) - mean * mean;
        mb[0] = (float)mean;
        mb[1] = (float)sqrt(var > 0.0 ? var : 0.0) + 1e-8f;
    }
    __syncthreads();
    int g = blockIdx.x * 256 + t;
    yv[g] = (yv[g] - mb[0]) / mb[1];
}

// ---------------------------------------------------------------------------
extern "C" void kernel_launch(void* const* d_in, const int* in_sizes, int n_in,
                              void* d_out, int out_size, void* d_ws,
                              size_t ws_size, hipStream_t stream)
{
    const float* X   = (const float*)d_in[0];
    const float* aw  = (const float*)d_in[1];
    const float* bw  = (const float*)d_in[2];
    const float* ham = (const float*)d_in[4];
    float* out = (float*)d_out;

    char* ws = (char*)d_ws;
    float2* W2     = (float2*)(ws + WS_W);
    float*  Txa    = (float*)(ws + WS_TXA);
    float*  Ty     = (float*)(ws + WS_TY);
    float*  Ez     = (float*)(ws + WS_EZ);
    float2* twg    = (float2*)(ws + WS_TW);
    double* part   = (double*)(ws + WS_PART);

    table_kernel<<<dim3(3, 64, 3), 256, 0, stream>>>(X, aw, bw, Txa, Ty, Ez, twg);
    density_fftz_kernel<<<256, 256, 0, stream>>>(Txa, Ty, Ez, twg, W2);
    plane_kernel<<<64, 512, 0, stream>>>(W2, ham, twg);
    invz_kernel<<<128, 256, 0, stream>>>(W2, twg, out, part);
    norm_kernel<<<1024, 256, 0, stream>>>(out, part);
}

// Round 4
// 40.844 us; speedup vs baseline: 2.3070x; 1.5985x over previous
//
#include <hip/hip_runtime.h>
#include <math.h>

#define NG (64*64*64)

typedef __bf16 v8bf __attribute__((ext_vector_type(8)));
typedef float  v4f  __attribute__((ext_vector_type(4)));

// ---- workspace layout (bytes) ----
#define WS_W    0                        // float2[NG]  2 MiB   (layout W2[kz][x][y])
#define WS_TXA  (2*1024*1024)            // f32[64][768] (aw folded)
#define WS_TY   (WS_TXA + 64*768*4)      // f32[64][768]
#define WS_EZH  (WS_TY  + 64*768*4)      // bf16[64][768]  EzT hi  (row = z, col = j)
#define WS_EZL  (WS_EZH + 64*768*2)      // bf16[64][768]  EzT lo
#define WS_TW   (WS_EZL + 64*768*2)      // float2[64] forward twiddles
#define WS_PART (WS_TW  + 64*8)          // double[256]

// ---------------------------------------------------------------------------
// K1: per-axis Gaussian tables (x: aw folded, f32; y: f32; z: transposed,
// hi/lo bf16 split for MFMA B-fragments) + forward twiddle table.
// grid 64 (c = coord idx) x 256, 3 j-chunks.
// ---------------------------------------------------------------------------
__global__ __launch_bounds__(256) void table_kernel(
    const float* __restrict__ X, const float* __restrict__ aw,
    const float* __restrict__ bw, float* __restrict__ Txa,
    float* __restrict__ Ty, __bf16* __restrict__ EzTh,
    __bf16* __restrict__ EzTl, float2* __restrict__ twg)
{
    int tid = threadIdx.x;
    int c = blockIdx.x;
    if (c == 0 && tid < 64) {
        float ang = -6.28318530717958647692f * (float)tid / 64.0f;
        float s, cs;
        sincosf(ang, &s, &cs);
        twg[tid] = make_float2(cs, s);
    }
    float pc = 0.5f * (float)c;
#pragma unroll
    for (int q = 0; q < 3; ++q) {
        int j = q * 256 + tid;              // 0..767
        int a = j / 6;
        float b = bw[j];
        float dx = pc - X[3 * a + 0];
        Txa[c * 768 + j] = __expf(b * dx * dx) * aw[j];
        float dy = pc - X[3 * a + 1];
        Ty[c * 768 + j] = __expf(b * dy * dy);
        float dz = pc - X[3 * a + 2];
        float ez = __expf(b * dz * dz);
        __bf16 h = (__bf16)ez;
        __bf16 l = (__bf16)(ez - (float)h);
        EzTh[c * 768 + j] = h;              // EzT[z=c][j]
        EzTl[c * 768 + j] = l;
    }
}

// ---------------------------------------------------------------------------
// 8-point DFT with folded constants. conj=true -> inverse sign.
// ---------------------------------------------------------------------------
__device__ __forceinline__ void dft8(const float xr[8], const float xi[8],
                                     float yr[8], float yi[8], bool conj)
{
    const float rt = 0.70710678118654752f;
    const float C[8]  = {1.f, rt, 0.f, -rt, -1.f, -rt, 0.f, rt};
    const float Sf[8] = {0.f, -rt, -1.f, -rt, 0.f, rt, 1.f, rt};
#pragma unroll
    for (int k = 0; k < 8; ++k) {
        float ar = 0.f, ai = 0.f;
#pragma unroll
        for (int n = 0; n < 8; ++n) {
            float c = C[(n * k) & 7];
            float s = conj ? -Sf[(n * k) & 7] : Sf[(n * k) & 7];
            ar += xr[n] * c - xi[n] * s;
            ai += xr[n] * s + xi[n] * c;
        }
        yr[k] = ar; yi[k] = ai;
    }
}

// 64-pt transform, radix 8x8, 8 threads/line. See round-2 comments.
__device__ __forceinline__ void xf64(const float2 xin[8], float2* L, int es,
                                     int t, bool conj, const float2* tw,
                                     float2 y[8], bool active)
{
    float br[8], bi[8];
    if (active) {
        float xr[8], xi[8];
#pragma unroll
        for (int n = 0; n < 8; ++n) { xr[n] = xin[n].x; xi[n] = xin[n].y; }
        dft8(xr, xi, br, bi, conj);
#pragma unroll
        for (int k1 = 0; k1 < 8; ++k1) {
            float2 wv = tw[(t * k1) & 63];
            float ws = conj ? -wv.y : wv.y;
            float tr = br[k1] * wv.x - bi[k1] * ws;
            float ti = br[k1] * ws + bi[k1] * wv.x;
            br[k1] = tr; bi[k1] = ti;
        }
#pragma unroll
        for (int k1 = 0; k1 < 8; ++k1)
            L[(k1 * 8 + t) * es] = make_float2(br[k1], bi[k1]);
    }
    __syncthreads();
    if (active) {
        float xr[8], xi[8];
#pragma unroll
        for (int n1 = 0; n1 < 8; ++n1) {
            float2 v = L[(t * 8 + n1) * es];
            xr[n1] = v.x; xi[n1] = v.y;
        }
        dft8(xr, xi, br, bi, conj);
#pragma unroll
        for (int k2 = 0; k2 < 8; ++k2) y[k2] = make_float2(br[k2], bi[k2]);
    }
}

// ---------------------------------------------------------------------------
// K2: MFMA density + forward z-FFT.
// Block = (x, y-quarter): C[16y][64z] = A[16y][768j] * B[768j][64z],
//   A[y][j] = Txa[x][j]*Ty[y][j] (built in LDS, hi/lo bf16 split),
//   B = EzT (global, hi/lo bf16, row=z col=j -> contiguous k fragments).
// 3 MFMAs per k-step (Ah*Bh + Ah*Bl + Al*Bh) recover f32 accuracy.
// Wave w owns z-slice [16w,16w+16). Then 16 z-lines FFT'd in LDS.
// ---------------------------------------------------------------------------
__global__ __launch_bounds__(256) void density_fftz_kernel(
    const float* __restrict__ Txa, const float* __restrict__ Ty,
    const __bf16* __restrict__ EzTh, const __bf16* __restrict__ EzTl,
    const float2* __restrict__ twg, float2* __restrict__ W2)
{
    __shared__ __align__(16) __bf16 Ah[16][776];   // +8 pad: uniform bank spread
    __shared__ __align__(16) __bf16 Al[16][776];
    __shared__ float2 D[16][66];
    __shared__ float2 tw[64];

    int tid = threadIdx.x;
    if (tid < 64) tw[tid] = twg[tid];

    int blk = blockIdx.x;
    int x  = blk >> 2;
    int yq = blk & 3;

    // ---- build A (hi/lo split) in LDS ----
    {
        int yl = tid >> 4;                 // 0..15
        int j0 = tid & 15;
        const float* txr = Txa + x * 768;
        const float* tyr = Ty + (yq * 16 + yl) * 768;
#pragma unroll 4
        for (int i = 0; i < 48; ++i) {
            int j = j0 + i * 16;
            float a = txr[j] * tyr[j];
            __bf16 h = (__bf16)a;
            Ah[yl][j] = h;
            Al[yl][j] = (__bf16)(a - (float)h);
        }
    }
    __syncthreads();

    // ---- GEMM: wave w -> C[0:16][16w:16w+16] ----
    int w = tid >> 6;
    int l = tid & 63;
    int m = l & 15;                        // A row (y) / B col (z) / C col
    int g = l >> 4;                        // k-group (8 consecutive k each)
    v4f accHH = {0.f, 0.f, 0.f, 0.f};
    v4f accHL = {0.f, 0.f, 0.f, 0.f};
    v4f accLH = {0.f, 0.f, 0.f, 0.f};
    const __bf16* bhp = EzTh + (w * 16 + m) * 768 + g * 8;
    const __bf16* blp = EzTl + (w * 16 + m) * 768 + g * 8;
#pragma unroll 4
    for (int ks = 0; ks < 24; ++ks) {
        v8bf aH = *(const v8bf*)&Ah[m][g * 8 + ks * 32];
        v8bf aL = *(const v8bf*)&Al[m][g * 8 + ks * 32];
        v8bf bH = *(const v8bf*)(bhp + ks * 32);
        v8bf bL = *(const v8bf*)(blp + ks * 32);
        accHH = __builtin_amdgcn_mfma_f32_16x16x32_bf16(aH, bH, accHH, 0, 0, 0);
        accHL = __builtin_amdgcn_mfma_f32_16x16x32_bf16(aH, bL, accHL, 0, 0, 0);
        accLH = __builtin_amdgcn_mfma_f32_16x16x32_bf16(aL, bH, accLH, 0, 0, 0);
    }
    // C layout: col = lane&15, row = (lane>>4)*4 + reg  [m89-verified]
#pragma unroll
    for (int r = 0; r < 4; ++r) {
        D[g * 4 + r][w * 16 + m] =
            make_float2(accHH[r] + accHL[r] + accLH[r], 0.f);
    }
    __syncthreads();

    // ---- forward z-FFT on the 16 lines (128 active threads) ----
    bool active = tid < 128;
    int lid = (tid >> 3) & 15, t = tid & 7;
    float2 xin[8], y[8];
    if (active) {
#pragma unroll
        for (int n2 = 0; n2 < 8; ++n2) xin[n2] = D[lid][8 * n2 + t];
    }
    xf64(xin, &D[lid][0], 1, t, false, tw, y, active);
    if (active) {
        int ybase = yq * 16 + lid;
#pragma unroll
        for (int k2 = 0; k2 < 8; ++k2)
            W2[(t + 8 * k2) * 4096 + x * 64 + ybase] = y[k2];
    }
}

// ---------------------------------------------------------------------------
// K3: per-kz plane kernel: fwd-y, fwd-x, xHamming, inv-x, inv-y, in LDS.
// ---------------------------------------------------------------------------
__global__ __launch_bounds__(512) void plane_kernel(
    float2* __restrict__ W2, const float* __restrict__ ham,
    const float2* __restrict__ twg)
{
    __shared__ float2 P[64][66];
    __shared__ float2 tw[64];
    int tid = threadIdx.x;
    if (tid < 64) tw[tid] = twg[tid];

    int z0 = blockIdx.x;
    const float4* src = (const float4*)(W2 + z0 * 4096);
#pragma unroll
    for (int q = 0; q < 4; ++q) {
        int i = tid + q * 512;
        float4 v = src[i];
        int e = i * 2;
        P[e >> 6][e & 63] = make_float2(v.x, v.y);
        P[e >> 6][(e & 63) + 1] = make_float2(v.z, v.w);
    }
    __syncthreads();

    int lid = tid >> 3, t = tid & 7;
    float2 xin[8], y[8];

    // forward y
#pragma unroll
    for (int n2 = 0; n2 < 8; ++n2) xin[n2] = P[lid][8 * n2 + t];
    xf64(xin, &P[lid][0], 1, t, false, tw, y, true);
    __syncthreads();
#pragma unroll
    for (int k2 = 0; k2 < 8; ++k2) P[lid][t + 8 * k2] = y[k2];
    __syncthreads();

    // forward x + Hamming
#pragma unroll
    for (int n2 = 0; n2 < 8; ++n2) xin[n2] = P[8 * n2 + t][lid];
    xf64(xin, &P[0][lid], 66, t, false, tw, y, true);
    {
        int hyz = ((lid + 32) & 63) * 64 + ((z0 + 32) & 63);
#pragma unroll
        for (int k2 = 0; k2 < 8; ++k2) {
            int kx = t + 8 * k2;
            float h = ham[((kx + 32) & 63) * 4096 + hyz];
            y[k2].x *= h; y[k2].y *= h;
        }
    }
    __syncthreads();
#pragma unroll
    for (int k2 = 0; k2 < 8; ++k2) P[t + 8 * k2][lid] = y[k2];
    __syncthreads();

    // inverse x
#pragma unroll
    for (int n2 = 0; n2 < 8; ++n2) xin[n2] = P[8 * n2 + t][lid];
    xf64(xin, &P[0][lid], 66, t, true, tw, y, true);
    __syncthreads();
#pragma unroll
    for (int k2 = 0; k2 < 8; ++k2) P[t + 8 * k2][lid] = y[k2];
    __syncthreads();

    // inverse y, write back
#pragma unroll
    for (int n2 = 0; n2 < 8; ++n2) xin[n2] = P[lid][8 * n2 + t];
    xf64(xin, &P[lid][0], 1, t, true, tw, y, true);
#pragma unroll
    for (int k2 = 0; k2 < 8; ++k2)
        W2[z0 * 4096 + lid * 64 + t + 8 * k2] = y[k2];
}

// ---------------------------------------------------------------------------
// K4: inverse z-FFT + real + 1/N^3 scale + per-block partial sums.
// ---------------------------------------------------------------------------
__global__ __launch_bounds__(256) void invz_kernel(
    const float2* __restrict__ W2, const float2* __restrict__ twg,
    float* __restrict__ outr, double* __restrict__ partial)
{
    __shared__ float2 ln[32][66];
    __shared__ float2 tw[64];
    __shared__ double red[8];
    int tid = threadIdx.x;
    if (tid < 64) tw[tid] = twg[tid];
    __syncthreads();

    int lid = tid >> 3, t = tid & 7;
    int L = blockIdx.x * 32 + lid;
    float2 xin[8], y[8];
#pragma unroll
    for (int n2 = 0; n2 < 8; ++n2) xin[n2] = W2[(8 * n2 + t) * 4096 + L];
    xf64(xin, &ln[lid][0], 1, t, true, tw, y, true);

    double s1 = 0.0, s2 = 0.0;
#pragma unroll
    for (int k2 = 0; k2 < 8; ++k2) {
        float v = y[k2].x * (1.0f / 262144.0f);
        outr[L * 64 + t + 8 * k2] = v;
        s1 += (double)v;
        s2 += (double)v * (double)v;
    }
#pragma unroll
    for (int off = 32; off > 0; off >>= 1) {
        s1 += __shfl_down(s1, off, 64);
        s2 += __shfl_down(s2, off, 64);
    }
    int lane = tid & 63, wv = tid >> 6;
    if (lane == 0) { red[wv * 2] = s1; red[wv * 2 + 1] = s2; }
    __syncthreads();
    if (tid == 0) {
        partial[blockIdx.x * 2 + 0] = red[0] + red[2] + red[4] + red[6];
        partial[blockIdx.x * 2 + 1] = red[1] + red[3] + red[5] + red[7];
    }
}

// ---------------------------------------------------------------------------
// K5: normalize with inlined final reduction over 128 block partials.
// ---------------------------------------------------------------------------
__global__ __launch_bounds__(256) void norm_kernel(
    float* __restrict__ yv, const double* __restrict__ partial)
{
    __shared__ double ls[128], ls2[128];
    __shared__ float mb[2];
    int t = threadIdx.x;
    if (t < 128) { ls[t] = partial[2 * t]; ls2[t] = partial[2 * t + 1]; }
    __syncthreads();
    for (int off = 64; off > 0; off >>= 1) {
        if (t < off) { ls[t] += ls[t + off]; ls2[t] += ls2[t + off]; }
        __syncthreads();
    }
    if (t == 0) {
        double mean = ls[0] * (1.0 / (double)NG);
        double var = ls2[0] * (1.0 / (double)NG) - mean * mean;
        mb[0] = (float)mean;
        mb[1] = (float)sqrt(var > 0.0 ? var : 0.0) + 1e-8f;
    }
    __syncthreads();
    int g = blockIdx.x * 256 + t;
    yv[g] = (yv[g] - mb[0]) / mb[1];
}

// ---------------------------------------------------------------------------
extern "C" void kernel_launch(void* const* d_in, const int* in_sizes, int n_in,
                              void* d_out, int out_size, void* d_ws,
                              size_t ws_size, hipStream_t stream)
{
    const float* X   = (const float*)d_in[0];
    const float* aw  = (const float*)d_in[1];
    const float* bw  = (const float*)d_in[2];
    const float* ham = (const float*)d_in[4];
    float* out = (float*)d_out;

    char* ws = (char*)d_ws;
    float2* W2     = (float2*)(ws + WS_W);
    float*  Txa    = (float*)(ws + WS_TXA);
    float*  Ty     = (float*)(ws + WS_TY);
    __bf16* EzTh   = (__bf16*)(ws + WS_EZH);
    __bf16* EzTl   = (__bf16*)(ws + WS_EZL);
    float2* twg    = (float2*)(ws + WS_TW);
    double* part   = (double*)(ws + WS_PART);

    table_kernel<<<64, 256, 0, stream>>>(X, aw, bw, Txa, Ty, EzTh, EzTl, twg);
    density_fftz_kernel<<<256, 256, 0, stream>>>(Txa, Ty, EzTh, EzTl, twg, W2);
    plane_kernel<<<64, 512, 0, stream>>>(W2, ham, twg);
    invz_kernel<<<128, 256, 0, stream>>>(W2, twg, out, part);
    norm_kernel<<<1024, 256, 0, stream>>>(out, part);
}

// Round 5
// 35.330 us; speedup vs baseline: 2.6670x; 1.1561x over previous
//
#include <hip/hip_runtime.h>
#include <math.h>

#define NG (64*64*64)

typedef __bf16 v8bf __attribute__((ext_vector_type(8)));
typedef float  v4f  __attribute__((ext_vector_type(4)));

// ---- workspace layout (bytes) ----
#define WS_W    0                        // float2[NG]  2 MiB   (layout W2[kz][x][y])
#define WS_TXA  (2*1024*1024)            // f32[64][768] (aw folded)
#define WS_TY   (WS_TXA + 64*768*4)      // f32[64][768]
#define WS_EZH  (WS_TY  + 64*768*4)      // bf16[64][768]  EzT hi  (row = z, col = j)
#define WS_EZL  (WS_EZH + 64*768*2)      // bf16[64][768]  EzT lo
#define WS_TW   (WS_EZL + 64*768*2)      // float2[64] forward twiddles
#define WS_PART (WS_TW  + 64*8)          // double[65]: [0..63] plane |G|^2, [64] DC

// ---------------------------------------------------------------------------
// K1: per-axis Gaussian tables (x: aw folded, f32; y: f32; z: transposed,
// hi/lo bf16 split for MFMA B-fragments) + forward twiddle table.
// ---------------------------------------------------------------------------
__global__ __launch_bounds__(256) void table_kernel(
    const float* __restrict__ X, const float* __restrict__ aw,
    const float* __restrict__ bw, float* __restrict__ Txa,
    float* __restrict__ Ty, __bf16* __restrict__ EzTh,
    __bf16* __restrict__ EzTl, float2* __restrict__ twg)
{
    int tid = threadIdx.x;
    int c = blockIdx.x;
    if (c == 0 && tid < 64) {
        float ang = -6.28318530717958647692f * (float)tid / 64.0f;
        float s, cs;
        sincosf(ang, &s, &cs);
        twg[tid] = make_float2(cs, s);
    }
    float pc = 0.5f * (float)c;
#pragma unroll
    for (int q = 0; q < 3; ++q) {
        int j = q * 256 + tid;              // 0..767
        int a = j / 6;
        float b = bw[j];
        float dx = pc - X[3 * a + 0];
        Txa[c * 768 + j] = __expf(b * dx * dx) * aw[j];
        float dy = pc - X[3 * a + 1];
        Ty[c * 768 + j] = __expf(b * dy * dy);
        float dz = pc - X[3 * a + 2];
        float ez = __expf(b * dz * dz);
        __bf16 h = (__bf16)ez;
        __bf16 l = (__bf16)(ez - (float)h);
        EzTh[c * 768 + j] = h;              // EzT[z=c][j]
        EzTl[c * 768 + j] = l;
    }
}

// ---------------------------------------------------------------------------
// Fast radix-2 8-point FFT, natural order in/out. CONJ=true -> inverse sign.
// ~60 real flops (explicit add/sub; +-i as swap/negate; rt twiddles folded).
// ---------------------------------------------------------------------------
__device__ __forceinline__ float2 cadd(float2 a, float2 b) {
    return make_float2(a.x + b.x, a.y + b.y);
}
__device__ __forceinline__ float2 csub(float2 a, float2 b) {
    return make_float2(a.x - b.x, a.y - b.y);
}
template <bool CONJ>
__device__ __forceinline__ float2 mulmi(float2 a) {   // *(-i) fwd, *(+i) inv
    return CONJ ? make_float2(-a.y, a.x) : make_float2(a.y, -a.x);
}

template <bool CONJ>
__device__ __forceinline__ void fft8(const float2 x[8], float2 y[8])
{
    const float r = 0.70710678118654752f;
    float2 ee0 = cadd(x[0], x[4]), ee1 = csub(x[0], x[4]);
    float2 eo0 = cadd(x[2], x[6]), eo1 = csub(x[2], x[6]);
    float2 E0 = cadd(ee0, eo0), E2 = csub(ee0, eo0);
    float2 me = mulmi<CONJ>(eo1);
    float2 E1 = cadd(ee1, me), E3 = csub(ee1, me);
    float2 oe0 = cadd(x[1], x[5]), oe1 = csub(x[1], x[5]);
    float2 oo0 = cadd(x[3], x[7]), oo1 = csub(x[3], x[7]);
    float2 O0 = cadd(oe0, oo0), O2 = csub(oe0, oo0);
    float2 mo = mulmi<CONJ>(oo1);
    float2 O1 = cadd(oe1, mo), O3 = csub(oe1, mo);
    float2 W1O1 = CONJ ? make_float2(r * (O1.x - O1.y), r * (O1.x + O1.y))
                       : make_float2(r * (O1.x + O1.y), r * (O1.y - O1.x));
    float2 W2O2 = mulmi<CONJ>(O2);
    float2 W3O3 = CONJ ? make_float2(-r * (O3.x + O3.y), r * (O3.x - O3.y))
                       : make_float2(r * (O3.y - O3.x), -r * (O3.x + O3.y));
    y[0] = cadd(E0, O0);   y[4] = csub(E0, O0);
    y[1] = cadd(E1, W1O1); y[5] = csub(E1, W1O1);
    y[2] = cadd(E2, W2O2); y[6] = csub(E2, W2O2);
    y[3] = cadd(E3, W3O3); y[7] = csub(E3, W3O3);
}

// 64-pt transform, radix 8x8, 8 threads/line. Input xin[n2] = element 8*n2+t.
// L[(...)*es] is the per-line exchange buffer (write slots == this thread's
// load slots -> no pre-barrier). Internal block barrier; ALL threads must
// call (inactive skip compute). Output y[k2] = element t+8*k2.
template <bool CONJ>
__device__ __forceinline__ void xf64(const float2 xin[8], float2* L, int es,
                                     int t, const float2* tw, float2 y[8],
                                     bool active)
{
    float2 b[8];
    if (active) {
        fft8<CONJ>(xin, b);
#pragma unroll
        for (int k1 = 0; k1 < 8; ++k1) {
            float2 wv = tw[(t * k1) & 63];
            float ws = CONJ ? -wv.y : wv.y;
            float tr = b[k1].x * wv.x - b[k1].y * ws;
            float ti = b[k1].x * ws + b[k1].y * wv.x;
            b[k1] = make_float2(tr, ti);
        }
#pragma unroll
        for (int k1 = 0; k1 < 8; ++k1)
            L[(k1 * 8 + t) * es] = b[k1];
    }
    __syncthreads();
    if (active) {
        float2 a[8];
#pragma unroll
        for (int n1 = 0; n1 < 8; ++n1) a[n1] = L[(t * 8 + n1) * es];
        fft8<CONJ>(a, y);
    }
}

// ---------------------------------------------------------------------------
// K2: MFMA density + forward z-FFT. (Unchanged structure from round 3.)
// ---------------------------------------------------------------------------
__global__ __launch_bounds__(256) void density_fftz_kernel(
    const float* __restrict__ Txa, const float* __restrict__ Ty,
    const __bf16* __restrict__ EzTh, const __bf16* __restrict__ EzTl,
    const float2* __restrict__ twg, float2* __restrict__ W2)
{
    __shared__ __align__(16) __bf16 Ah[16][776];
    __shared__ __align__(16) __bf16 Al[16][776];
    __shared__ float2 D[16][66];
    __shared__ float2 tw[64];

    int tid = threadIdx.x;
    if (tid < 64) tw[tid] = twg[tid];

    int blk = blockIdx.x;
    int x  = blk >> 2;
    int yq = blk & 3;

    // ---- build A (hi/lo split) in LDS ----
    {
        int yl = tid >> 4;
        int j0 = tid & 15;
        const float* txr = Txa + x * 768;
        const float* tyr = Ty + (yq * 16 + yl) * 768;
#pragma unroll 4
        for (int i = 0; i < 48; ++i) {
            int j = j0 + i * 16;
            float a = txr[j] * tyr[j];
            __bf16 h = (__bf16)a;
            Ah[yl][j] = h;
            Al[yl][j] = (__bf16)(a - (float)h);
        }
    }
    __syncthreads();

    // ---- GEMM: wave w -> C[0:16][16w:16w+16] ----
    int w = tid >> 6;
    int l = tid & 63;
    int m = l & 15;
    int g = l >> 4;
    v4f accHH = {0.f, 0.f, 0.f, 0.f};
    v4f accHL = {0.f, 0.f, 0.f, 0.f};
    v4f accLH = {0.f, 0.f, 0.f, 0.f};
    const __bf16* bhp = EzTh + (w * 16 + m) * 768 + g * 8;
    const __bf16* blp = EzTl + (w * 16 + m) * 768 + g * 8;
#pragma unroll 4
    for (int ks = 0; ks < 24; ++ks) {
        v8bf aH = *(const v8bf*)&Ah[m][g * 8 + ks * 32];
        v8bf aL = *(const v8bf*)&Al[m][g * 8 + ks * 32];
        v8bf bH = *(const v8bf*)(bhp + ks * 32);
        v8bf bL = *(const v8bf*)(blp + ks * 32);
        accHH = __builtin_amdgcn_mfma_f32_16x16x32_bf16(aH, bH, accHH, 0, 0, 0);
        accHL = __builtin_amdgcn_mfma_f32_16x16x32_bf16(aH, bL, accHL, 0, 0, 0);
        accLH = __builtin_amdgcn_mfma_f32_16x16x32_bf16(aL, bH, accLH, 0, 0, 0);
    }
#pragma unroll
    for (int r = 0; r < 4; ++r) {
        D[g * 4 + r][w * 16 + m] =
            make_float2(accHH[r] + accHL[r] + accLH[r], 0.f);
    }
    __syncthreads();

    // ---- forward z-FFT on the 16 lines (128 active threads) ----
    bool active = tid < 128;
    int lid = (tid >> 3) & 15, t = tid & 7;
    float2 xin[8], y[8];
    if (active) {
#pragma unroll
        for (int n2 = 0; n2 < 8; ++n2) xin[n2] = D[lid][8 * n2 + t];
    }
    xf64<false>(xin, &D[lid][0], 1, t, tw, y, active);
    if (active) {
        int ybase = yq * 16 + lid;
#pragma unroll
        for (int k2 = 0; k2 < 8; ++k2)
            W2[(t + 8 * k2) * 4096 + x * 64 + ybase] = y[k2];
    }
}

// ---------------------------------------------------------------------------
// K3: per-kz plane: fwd-y, fwd-x, xHamming (+ DC extract + |G|^2 partial),
// inv-x, inv-y. 64 blocks x 512 threads.
// ---------------------------------------------------------------------------
__global__ __launch_bounds__(512) void plane_kernel(
    float2* __restrict__ W2, const float* __restrict__ ham,
    const float2* __restrict__ twg, double* __restrict__ partial)
{
    __shared__ float2 P[64][66];
    __shared__ float2 tw[64];
    __shared__ double red[8];
    int tid = threadIdx.x;
    if (tid < 64) tw[tid] = twg[tid];

    int z0 = blockIdx.x;
    const float4* src = (const float4*)(W2 + z0 * 4096);
#pragma unroll
    for (int q = 0; q < 4; ++q) {
        int i = tid + q * 512;
        float4 v = src[i];
        int e = i * 2;
        P[e >> 6][e & 63] = make_float2(v.x, v.y);
        P[e >> 6][(e & 63) + 1] = make_float2(v.z, v.w);
    }
    __syncthreads();

    int lid = tid >> 3, t = tid & 7;
    float2 xin[8], y[8];

    // forward y (lines = rows x = lid)
#pragma unroll
    for (int n2 = 0; n2 < 8; ++n2) xin[n2] = P[lid][8 * n2 + t];
    xf64<false>(xin, &P[lid][0], 1, t, tw, y, true);
    __syncthreads();
#pragma unroll
    for (int k2 = 0; k2 < 8; ++k2) P[lid][t + 8 * k2] = y[k2];
    __syncthreads();

    // forward x (lines = columns ky = lid) + Hamming
#pragma unroll
    for (int n2 = 0; n2 < 8; ++n2) xin[n2] = P[8 * n2 + t][lid];
    xf64<false>(xin, &P[0][lid], 66, t, tw, y, true);
    {
        int hyz = ((lid + 32) & 63) * 64 + ((z0 + 32) & 63);
#pragma unroll
        for (int k2 = 0; k2 < 8; ++k2) {
            int kx = t + 8 * k2;
            float h = ham[((kx + 32) & 63) * 4096 + hyz];
            y[k2].x *= h; y[k2].y *= h;
        }
    }
    // ---- Parseval partial: sum |G|^2 over this plane; grab DC coeff ----
    {
        double s2 = 0.0;
#pragma unroll
        for (int k2 = 0; k2 < 8; ++k2)
            s2 += (double)y[k2].x * y[k2].x + (double)y[k2].y * y[k2].y;
#pragma unroll
        for (int off = 32; off > 0; off >>= 1)
            s2 += __shfl_down(s2, off, 64);
        if ((tid & 63) == 0) red[tid >> 6] = s2;
        if (z0 == 0 && tid == 0)                  // kx=0, ky=0, kz=0
            partial[64] = (double)y[0].x;
    }
    __syncthreads();
#pragma unroll
    for (int k2 = 0; k2 < 8; ++k2) P[t + 8 * k2][lid] = y[k2];
    __syncthreads();
    if (tid == 0) {
        double s = 0.0;
#pragma unroll
        for (int i = 0; i < 8; ++i) s += red[i];
        partial[z0] = s;
    }

    // inverse x
#pragma unroll
    for (int n2 = 0; n2 < 8; ++n2) xin[n2] = P[8 * n2 + t][lid];
    xf64<true>(xin, &P[0][lid], 66, t, tw, y, true);
    __syncthreads();
#pragma unroll
    for (int k2 = 0; k2 < 8; ++k2) P[t + 8 * k2][lid] = y[k2];
    __syncthreads();

    // inverse y, write back
#pragma unroll
    for (int n2 = 0; n2 < 8; ++n2) xin[n2] = P[lid][8 * n2 + t];
    xf64<true>(xin, &P[lid][0], 1, t, tw, y, true);
#pragma unroll
    for (int k2 = 0; k2 < 8; ++k2)
        W2[z0 * 4096 + lid * 64 + t + 8 * k2] = y[k2];
}

// ---------------------------------------------------------------------------
// K4: inverse z-FFT + real + scale + NORMALIZE (mean/std from Parseval/DC:
// mean = G0/N^3, var = Sum|G|^2/N^6 - mean^2). 128 blocks x 256 threads.
// ---------------------------------------------------------------------------
__global__ __launch_bounds__(256) void invz_norm_kernel(
    const float2* __restrict__ W2, const float2* __restrict__ twg,
    const double* __restrict__ partial, float* __restrict__ outr)
{
    __shared__ float2 ln[32][66];
    __shared__ float2 tw[64];
    __shared__ float nrm[2];
    int tid = threadIdx.x;
    if (tid < 64) tw[tid] = twg[tid];
    if (tid >= 64 && tid < 128) {
        double s = partial[tid - 64];
#pragma unroll
        for (int off = 32; off > 0; off >>= 1)
            s += __shfl_down(s, off, 64);
        if (tid == 64) {
            double mean = partial[64] * (1.0 / 262144.0);
            double var = s * (1.0 / 262144.0 / 262144.0) - mean * mean;
            nrm[0] = (float)mean;
            nrm[1] = (float)(1.0 / (sqrt(var > 0.0 ? var : 0.0) + 1e-8));
        }
    }
    __syncthreads();

    int lid = tid >> 3, t = tid & 7;
    int L = blockIdx.x * 32 + lid;
    float2 xin[8], y[8];
#pragma unroll
    for (int n2 = 0; n2 < 8; ++n2) xin[n2] = W2[(8 * n2 + t) * 4096 + L];
    xf64<true>(xin, &ln[lid][0], 1, t, tw, y, true);

    float mean = nrm[0], rstd = nrm[1];
#pragma unroll
    for (int k2 = 0; k2 < 8; ++k2) {
        float v = y[k2].x * (1.0f / 262144.0f);
        outr[L * 64 + t + 8 * k2] = (v - mean) * rstd;
    }
}

// ---------------------------------------------------------------------------
extern "C" void kernel_launch(void* const* d_in, const int* in_sizes, int n_in,
                              void* d_out, int out_size, void* d_ws,
                              size_t ws_size, hipStream_t stream)
{
    const float* X   = (const float*)d_in[0];
    const float* aw  = (const float*)d_in[1];
    const float* bw  = (const float*)d_in[2];
    const float* ham = (const float*)d_in[4];
    float* out = (float*)d_out;

    char* ws = (char*)d_ws;
    float2* W2     = (float2*)(ws + WS_W);
    float*  Txa    = (float*)(ws + WS_TXA);
    float*  Ty     = (float*)(ws + WS_TY);
    __bf16* EzTh   = (__bf16*)(ws + WS_EZH);
    __bf16* EzTl   = (__bf16*)(ws + WS_EZL);
    float2* twg    = (float2*)(ws + WS_TW);
    double* part   = (double*)(ws + WS_PART);

    table_kernel<<<64, 256, 0, stream>>>(X, aw, bw, Txa, Ty, EzTh, EzTl, twg);
    density_fftz_kernel<<<256, 256, 0, stream>>>(Txa, Ty, EzTh, EzTl, twg, W2);
    plane_kernel<<<64, 512, 0, stream>>>(W2, ham, twg, part);
    invz_norm_kernel<<<128, 256, 0, stream>>>(W2, twg, part, out);
}

// Round 6
// 34.035 us; speedup vs baseline: 2.7685x; 1.0380x over previous
//
#include <hip/hip_runtime.h>
#include <math.h>

#define NG (64*64*64)

typedef __bf16 v8bf __attribute__((ext_vector_type(8)));
typedef float  v4f  __attribute__((ext_vector_type(4)));

// ---- workspace layout (bytes) ----
#define WS_W    0                        // float2[NG]  2 MiB   (layout W2[kz][x][y])
#define WS_EZH  (2*1024*1024)            // bf16[64][768]  EzT hi (row = z, col = j)
#define WS_EZL  (WS_EZH + 64*768*2)      // bf16[64][768]  EzT lo
#define WS_TW   (WS_EZL + 64*768*2)      // float2[64] forward twiddles
#define WS_PART (WS_TW  + 64*8)          // double[65]: [0..63] plane |G|^2, [64] DC

// ---------------------------------------------------------------------------
// K0: EzT (z-axis Gaussian factors, transposed, hi/lo bf16) + twiddles.
// 64 blocks (c = z coord) x 256 threads, 3 j per thread.
// ---------------------------------------------------------------------------
__global__ __launch_bounds__(256) void ez_tw_kernel(
    const float* __restrict__ X, const float* __restrict__ bw,
    __bf16* __restrict__ EzTh, __bf16* __restrict__ EzTl,
    float2* __restrict__ twg)
{
    int tid = threadIdx.x;
    int c = blockIdx.x;
    if (c == 0 && tid < 64) {
        float ang = -6.28318530717958647692f * (float)tid / 64.0f;
        float s, cs;
        sincosf(ang, &s, &cs);
        twg[tid] = make_float2(cs, s);
    }
    float pc = 0.5f * (float)c;
#pragma unroll
    for (int q = 0; q < 3; ++q) {
        int j = q * 256 + tid;              // 0..767
        int a = j / 6;
        float dz = pc - X[3 * a + 2];
        float ez = __expf(bw[j] * dz * dz);
        __bf16 h = (__bf16)ez;
        __bf16 l = (__bf16)(ez - (float)h);
        EzTh[c * 768 + j] = h;
        EzTl[c * 768 + j] = l;
    }
}

// ---------------------------------------------------------------------------
// Fast radix-2 8-point FFT, natural order in/out. CONJ=true -> inverse sign.
// ---------------------------------------------------------------------------
__device__ __forceinline__ float2 cadd(float2 a, float2 b) {
    return make_float2(a.x + b.x, a.y + b.y);
}
__device__ __forceinline__ float2 csub(float2 a, float2 b) {
    return make_float2(a.x - b.x, a.y - b.y);
}
template <bool CONJ>
__device__ __forceinline__ float2 mulmi(float2 a) {   // *(-i) fwd, *(+i) inv
    return CONJ ? make_float2(-a.y, a.x) : make_float2(a.y, -a.x);
}

template <bool CONJ>
__device__ __forceinline__ void fft8(const float2 x[8], float2 y[8])
{
    const float r = 0.70710678118654752f;
    float2 ee0 = cadd(x[0], x[4]), ee1 = csub(x[0], x[4]);
    float2 eo0 = cadd(x[2], x[6]), eo1 = csub(x[2], x[6]);
    float2 E0 = cadd(ee0, eo0), E2 = csub(ee0, eo0);
    float2 me = mulmi<CONJ>(eo1);
    float2 E1 = cadd(ee1, me), E3 = csub(ee1, me);
    float2 oe0 = cadd(x[1], x[5]), oe1 = csub(x[1], x[5]);
    float2 oo0 = cadd(x[3], x[7]), oo1 = csub(x[3], x[7]);
    float2 O0 = cadd(oe0, oo0), O2 = csub(oe0, oo0);
    float2 mo = mulmi<CONJ>(oo1);
    float2 O1 = cadd(oe1, mo), O3 = csub(oe1, mo);
    float2 W1O1 = CONJ ? make_float2(r * (O1.x - O1.y), r * (O1.x + O1.y))
                       : make_float2(r * (O1.x + O1.y), r * (O1.y - O1.x));
    float2 W2O2 = mulmi<CONJ>(O2);
    float2 W3O3 = CONJ ? make_float2(-r * (O3.x + O3.y), r * (O3.x - O3.y))
                       : make_float2(r * (O3.y - O3.x), -r * (O3.x + O3.y));
    y[0] = cadd(E0, O0);   y[4] = csub(E0, O0);
    y[1] = cadd(E1, W1O1); y[5] = csub(E1, W1O1);
    y[2] = cadd(E2, W2O2); y[6] = csub(E2, W2O2);
    y[3] = cadd(E3, W3O3); y[7] = csub(E3, W3O3);
}

// 64-pt transform, radix 8x8, 8 threads/line. Input xin[n2] = element 8*n2+t.
// L[(...)*es] is the per-line exchange buffer (each thread writes exactly the
// slots it read -> no pre-barrier). Internal block barrier; ALL threads must
// call (inactive skip compute). Output y[k2] = element t+8*k2.
template <bool CONJ>
__device__ __forceinline__ void xf64(const float2 xin[8], float2* L, int es,
                                     int t, const float2* tw, float2 y[8],
                                     bool active)
{
    float2 b[8];
    if (active) {
        fft8<CONJ>(xin, b);
#pragma unroll
        for (int k1 = 0; k1 < 8; ++k1) {
            float2 wv = tw[(t * k1) & 63];
            float ws = CONJ ? -wv.y : wv.y;
            float tr = b[k1].x * wv.x - b[k1].y * ws;
            float ti = b[k1].x * ws + b[k1].y * wv.x;
            b[k1] = make_float2(tr, ti);
        }
#pragma unroll
        for (int k1 = 0; k1 < 8; ++k1)
            L[(k1 * 8 + t) * es] = b[k1];
    }
    __syncthreads();
    if (active) {
        float2 a[8];
#pragma unroll
        for (int n1 = 0; n1 < 8; ++n1) a[n1] = L[(t * 8 + n1) * es];
        fft8<CONJ>(a, y);
    }
}

// ---------------------------------------------------------------------------
// K1: density (A computed in-register, MFMA, K-split over 8 waves) + fwd z-FFT.
// Block = (x, y-quarter), 512 threads, 256 blocks.
//   A[y][j] = aw[j]*exp(bw[j]*(dx^2+dy^2))   (hi/lo bf16 in LDS)
//   C[16y][64z] = A[16][768] * EzT^T[768][64]; waves 0-3: k<384 -> D.x,
//   waves 4-7: k>=384 -> D.y; FFT sums .x+.y.
// ---------------------------------------------------------------------------
__global__ __launch_bounds__(512) void density_fftz_kernel(
    const float* __restrict__ X, const float* __restrict__ aw,
    const float* __restrict__ bw, const __bf16* __restrict__ EzTh,
    const __bf16* __restrict__ EzTl, const float2* __restrict__ twg,
    float2* __restrict__ W2)
{
    __shared__ __align__(16) __bf16 Ah[16][776];
    __shared__ __align__(16) __bf16 Al[16][776];
    __shared__ float2 D[16][66];
    __shared__ float2 tw[64];

    int tid = threadIdx.x;
    if (tid < 64) tw[tid] = twg[tid];

    int blk = blockIdx.x;
    int x  = blk >> 2;
    int yq = blk & 3;
    float px = 0.5f * (float)x;

    // ---- build A in-register: thread -> (row, 4 atoms x 6 terms) ----
    {
        int row = tid >> 5;                 // 0..15
        int a0  = (tid & 31) * 4;           // 4 atoms -> 24 consecutive j
        float py = 0.5f * (float)(yq * 16 + row);
#pragma unroll
        for (int ai = 0; ai < 4; ++ai) {
            int a = a0 + ai;
            float dxa = px - X[3 * a + 0];
            float dya = py - X[3 * a + 1];
            float d2 = dxa * dxa + dya * dya;
            int jb = a * 6;
#pragma unroll
            for (int p = 0; p < 3; ++p) {   // 3 packed pairs
                int j = jb + 2 * p;
                float e0 = aw[j] * __expf(bw[j] * d2);
                float e1 = aw[j + 1] * __expf(bw[j + 1] * d2);
                __bf16 h0 = (__bf16)e0, h1 = (__bf16)e1;
                __bf16 l0 = (__bf16)(e0 - (float)h0);
                __bf16 l1 = (__bf16)(e1 - (float)h1);
                unsigned hp = ((unsigned)__builtin_bit_cast(unsigned short, h1) << 16)
                            | (unsigned)__builtin_bit_cast(unsigned short, h0);
                unsigned lp = ((unsigned)__builtin_bit_cast(unsigned short, l1) << 16)
                            | (unsigned)__builtin_bit_cast(unsigned short, l0);
                *(unsigned*)&Ah[row][j] = hp;
                *(unsigned*)&Al[row][j] = lp;
            }
        }
    }
    __syncthreads();

    // ---- GEMM: wave w -> z-tile (w&3), k-half (w>>2) ----
    {
        int w = tid >> 6;
        int l = tid & 63;
        int m = l & 15;                     // A row (y) / B row (z) / C col
        int g = l >> 4;                     // k-group (8 consecutive k)
        int zt = w & 3;
        int kh = w >> 2;
        v4f accHH = {0.f, 0.f, 0.f, 0.f};
        v4f accHL = {0.f, 0.f, 0.f, 0.f};
        v4f accLH = {0.f, 0.f, 0.f, 0.f};
        const __bf16* bhp = EzTh + (zt * 16 + m) * 768 + kh * 384 + g * 8;
        const __bf16* blp = EzTl + (zt * 16 + m) * 768 + kh * 384 + g * 8;
        const __bf16* ahp = &Ah[m][kh * 384 + g * 8];
        const __bf16* alp = &Al[m][kh * 384 + g * 8];
#pragma unroll 4
        for (int ks = 0; ks < 12; ++ks) {
            v8bf aH = *(const v8bf*)(ahp + ks * 32);
            v8bf aL = *(const v8bf*)(alp + ks * 32);
            v8bf bH = *(const v8bf*)(bhp + ks * 32);
            v8bf bL = *(const v8bf*)(blp + ks * 32);
            accHH = __builtin_amdgcn_mfma_f32_16x16x32_bf16(aH, bH, accHH, 0, 0, 0);
            accHL = __builtin_amdgcn_mfma_f32_16x16x32_bf16(aH, bL, accHL, 0, 0, 0);
            accLH = __builtin_amdgcn_mfma_f32_16x16x32_bf16(aL, bH, accLH, 0, 0, 0);
        }
        // C layout: col = lane&15, row = (lane>>4)*4 + reg  [m89-verified]
#pragma unroll
        for (int r = 0; r < 4; ++r) {
            float s = accHH[r] + accHL[r] + accLH[r];
            if (kh == 0) D[g * 4 + r][zt * 16 + m].x = s;
            else         D[g * 4 + r][zt * 16 + m].y = s;
        }
    }
    __syncthreads();

    // ---- forward z-FFT on the 16 lines (128 active threads) ----
    bool active = tid < 128;
    int lid = (tid >> 3) & 15, t = tid & 7;
    float2 xin[8], y[8];
    if (active) {
#pragma unroll
        for (int n2 = 0; n2 < 8; ++n2) {
            float2 v = D[lid][8 * n2 + t];
            xin[n2] = make_float2(v.x + v.y, 0.f);   // sum k-halves
        }
    }
    xf64<false>(xin, &D[lid][0], 1, t, tw, y, active);
    if (active) {
        int ybase = yq * 16 + lid;
#pragma unroll
        for (int k2 = 0; k2 < 8; ++k2)
            W2[(t + 8 * k2) * 4096 + x * 64 + ybase] = y[k2];
    }
}

// ---------------------------------------------------------------------------
// K2: per-kz plane: fwd-y, fwd-x, xHamming (+ DC extract + |G|^2 partial),
// inv-x, inv-y. 64 blocks x 512 threads.
// ---------------------------------------------------------------------------
__global__ __launch_bounds__(512) void plane_kernel(
    float2* __restrict__ W2, const float* __restrict__ ham,
    const float2* __restrict__ twg, double* __restrict__ partial)
{
    __shared__ float2 P[64][66];
    __shared__ float2 tw[64];
    __shared__ double red[8];
    int tid = threadIdx.x;
    if (tid < 64) tw[tid] = twg[tid];

    int z0 = blockIdx.x;
    const float4* src = (const float4*)(W2 + z0 * 4096);
#pragma unroll
    for (int q = 0; q < 4; ++q) {
        int i = tid + q * 512;
        float4 v = src[i];
        int e = i * 2;
        P[e >> 6][e & 63] = make_float2(v.x, v.y);
        P[e >> 6][(e & 63) + 1] = make_float2(v.z, v.w);
    }
    __syncthreads();

    int lid = tid >> 3, t = tid & 7;
    float2 xin[8], y[8];

    // forward y (lines = rows x = lid)
#pragma unroll
    for (int n2 = 0; n2 < 8; ++n2) xin[n2] = P[lid][8 * n2 + t];
    xf64<false>(xin, &P[lid][0], 1, t, tw, y, true);
    __syncthreads();
#pragma unroll
    for (int k2 = 0; k2 < 8; ++k2) P[lid][t + 8 * k2] = y[k2];
    __syncthreads();

    // forward x (lines = columns ky = lid) + Hamming
#pragma unroll
    for (int n2 = 0; n2 < 8; ++n2) xin[n2] = P[8 * n2 + t][lid];
    xf64<false>(xin, &P[0][lid], 66, t, tw, y, true);
    {
        int hyz = ((lid + 32) & 63) * 64 + ((z0 + 32) & 63);
#pragma unroll
        for (int k2 = 0; k2 < 8; ++k2) {
            int kx = t + 8 * k2;
            float h = ham[((kx + 32) & 63) * 4096 + hyz];
            y[k2].x *= h; y[k2].y *= h;
        }
    }
    // ---- Parseval partial: sum |G|^2 over this plane; grab DC coeff ----
    {
        double s2 = 0.0;
#pragma unroll
        for (int k2 = 0; k2 < 8; ++k2)
            s2 += (double)y[k2].x * y[k2].x + (double)y[k2].y * y[k2].y;
#pragma unroll
        for (int off = 32; off > 0; off >>= 1)
            s2 += __shfl_down(s2, off, 64);
        if ((tid & 63) == 0) red[tid >> 6] = s2;
        if (z0 == 0 && tid == 0)                  // kx=0, ky=0, kz=0
            partial[64] = (double)y[0].x;
    }
    __syncthreads();
#pragma unroll
    for (int k2 = 0; k2 < 8; ++k2) P[t + 8 * k2][lid] = y[k2];
    __syncthreads();
    if (tid == 0) {
        double s = 0.0;
#pragma unroll
        for (int i = 0; i < 8; ++i) s += red[i];
        partial[z0] = s;
    }

    // inverse x
#pragma unroll
    for (int n2 = 0; n2 < 8; ++n2) xin[n2] = P[8 * n2 + t][lid];
    xf64<true>(xin, &P[0][lid], 66, t, tw, y, true);
    __syncthreads();
#pragma unroll
    for (int k2 = 0; k2 < 8; ++k2) P[t + 8 * k2][lid] = y[k2];
    __syncthreads();

    // inverse y, write back
#pragma unroll
    for (int n2 = 0; n2 < 8; ++n2) xin[n2] = P[lid][8 * n2 + t];
    xf64<true>(xin, &P[lid][0], 1, t, tw, y, true);
#pragma unroll
    for (int k2 = 0; k2 < 8; ++k2)
        W2[z0 * 4096 + lid * 64 + t + 8 * k2] = y[k2];
}

// ---------------------------------------------------------------------------
// K3: inverse z-FFT + real + scale + NORMALIZE (mean/std from Parseval/DC).
// 128 blocks x 256 threads.
// ---------------------------------------------------------------------------
__global__ __launch_bounds__(256) void invz_norm_kernel(
    const float2* __restrict__ W2, const float2* __restrict__ twg,
    const double* __restrict__ partial, float* __restrict__ outr)
{
    __shared__ float2 ln[32][66];
    __shared__ float2 tw[64];
    __shared__ float nrm[2];
    int tid = threadIdx.x;
    if (tid < 64) tw[tid] = twg[tid];
    if (tid >= 64 && tid < 128) {
        double s = partial[tid - 64];
#pragma unroll
        for (int off = 32; off > 0; off >>= 1)
            s += __shfl_down(s, off, 64);
        if (tid == 64) {
            double mean = partial[64] * (1.0 / 262144.0);
            double var = s * (1.0 / 262144.0 / 262144.0) - mean * mean;
            nrm[0] = (float)mean;
            nrm[1] = (float)(1.0 / (sqrt(var > 0.0 ? var : 0.0) + 1e-8));
        }
    }
    __syncthreads();

    int lid = tid >> 3, t = tid & 7;
    int L = blockIdx.x * 32 + lid;
    float2 xin[8], y[8];
#pragma unroll
    for (int n2 = 0; n2 < 8; ++n2) xin[n2] = W2[(8 * n2 + t) * 4096 + L];
    xf64<true>(xin, &ln[lid][0], 1, t, tw, y, true);

    float mean = nrm[0], rstd = nrm[1];
#pragma unroll
    for (int k2 = 0; k2 < 8; ++k2) {
        float v = y[k2].x * (1.0f / 262144.0f);
        outr[L * 64 + t + 8 * k2] = (v - mean) * rstd;
    }
}

// ---------------------------------------------------------------------------
extern "C" void kernel_launch(void* const* d_in, const int* in_sizes, int n_in,
                              void* d_out, int out_size, void* d_ws,
                              size_t ws_size, hipStream_t stream)
{
    const float* X   = (const float*)d_in[0];
    const float* aw  = (const float*)d_in[1];
    const float* bw  = (const float*)d_in[2];
    const float* ham = (const float*)d_in[4];
    float* out = (float*)d_out;

    char* ws = (char*)d_ws;
    float2* W2     = (float2*)(ws + WS_W);
    __bf16* EzTh   = (__bf16*)(ws + WS_EZH);
    __bf16* EzTl   = (__bf16*)(ws + WS_EZL);
    float2* twg    = (float2*)(ws + WS_TW);
    double* part   = (double*)(ws + WS_PART);

    ez_tw_kernel<<<64, 256, 0, stream>>>(X, bw, EzTh, EzTl, twg);
    density_fftz_kernel<<<256, 512, 0, stream>>>(X, aw, bw, EzTh, EzTl, twg, W2);
    plane_kernel<<<64, 512, 0, stream>>>(W2, ham, twg, part);
    invz_norm_kernel<<<128, 256, 0, stream>>>(W2, twg, part, out);
}